// Round 6
// baseline (481.298 us; speedup 1.0000x reference)
//
#include <hip/hip_runtime.h>

#define B_ 8
#define T_ 8192
#define D_ 1024
#define GD_ 64
#define WSZ_ 16
#define NWIN_ (T_ / WSZ_)   // 512

// ---------------------------------------------------------------------------
// K1 (fused, barrier-free): sims of g = normalize(relu(z@W1)@W2).
// Block = 256 thr = 4 INDEPENDENT waves. Each wave owns 16 tokens (= one
// window): stages its own z chunk (64 k) into a private padded LDS buffer
// (reg-staged, next chunk prefetched into regs during compute), reads the
// B-operand (W1/W2) directly from global (L1-resident, lane-broadcast).
// No __syncthreads anywhere; same-wave DS ordering guarantees correctness.
// Per lane: 2 tokens x 8 gd. Precision = validated R4 class: f32 FMA within
// each 64-k chunk, f32 chunk->total accumulation, f32-rounded H and G,
// f64 norms and sims.
// ---------------------------------------------------------------------------
__global__ __launch_bounds__(256) void k_sims(
    const float* __restrict__ z, const float* __restrict__ W1,
    const float* __restrict__ W2, double* __restrict__ sims_out)
{
  __shared__ float Zb[4][16][68];   // per-wave token buffer (z / H / g)

  const int tid = threadIdx.x;
  const int wv = tid >> 6;
  const int lane = tid & 63;
  const int tp = lane >> 3;         // 0..7 -> tokens 2tp, 2tp+1
  const int gs = lane & 7;          // 0..7 -> gd 8gs..8gs+7
  const long wtb = (long)blockIdx.x * 64 + wv * 16;   // wave token base

  const int srow = lane >> 4;       // staging row base (0..3), +4j
  const int sq = lane & 15;         // staging k-quad

  // ---- prefetch chunk 0 into registers
  float4 zr[4];
#pragma unroll
  for (int j = 0; j < 4; ++j)
    zr[j] = *(const float4*)(z + (wtb + srow + 4 * j) * D_ + 4 * sq);

  float acc[2][8];
#pragma unroll
  for (int i = 0; i < 2; ++i)
#pragma unroll
    for (int n = 0; n < 8; ++n) acc[i][n] = 0.0f;

  // ================= phase A: H = z @ W1 ==================================
#pragma unroll 1
  for (int c = 0; c < 16; ++c) {
    // write staged chunk c (waits vmcnt on zr)
#pragma unroll
    for (int j = 0; j < 4; ++j)
      *(float4*)&Zb[wv][srow + 4 * j][4 * sq] = zr[j];
    // prefetch chunk c+1
    if (c < 15) {
#pragma unroll
      for (int j = 0; j < 4; ++j)
        zr[j] = *(const float4*)(z + (wtb + srow + 4 * j) * D_ +
                                 (c + 1) * 64 + 4 * sq);
    }

    float cacc[2][8];
#pragma unroll
    for (int i = 0; i < 2; ++i)
#pragma unroll
      for (int n = 0; n < 8; ++n) cacc[i][n] = 0.0f;

#pragma unroll 2
    for (int kq = 0; kq < 16; ++kq) {
      const float4 a0 = *(const float4*)&Zb[wv][2 * tp][4 * kq];
      const float4 a1 = *(const float4*)&Zb[wv][2 * tp + 1][4 * kq];
      const float a0v[4] = {a0.x, a0.y, a0.z, a0.w};
      const float a1v[4] = {a1.x, a1.y, a1.z, a1.w};
      const float* wr = W1 + (long)(c * 64 + 4 * kq) * GD_ + 8 * gs;
#pragma unroll
      for (int dk = 0; dk < 4; ++dk) {
        const float4 b0 = *(const float4*)(wr + dk * GD_);
        const float4 b1 = *(const float4*)(wr + dk * GD_ + 4);
        const float bv[8] = {b0.x, b0.y, b0.z, b0.w, b1.x, b1.y, b1.z, b1.w};
#pragma unroll
        for (int n = 0; n < 8; ++n) {
          cacc[0][n] = fmaf(a0v[dk], bv[n], cacc[0][n]);
          cacc[1][n] = fmaf(a1v[dk], bv[n], cacc[1][n]);
        }
      }
    }
#pragma unroll
    for (int i = 0; i < 2; ++i)
#pragma unroll
      for (int n = 0; n < 8; ++n) acc[i][n] += cacc[i][n];
  }

  // ---- H = relu(.), f32, write into Zb (2 rows x 2 float4 per lane)
#pragma unroll
  for (int i = 0; i < 2; ++i) {
    float4 h0, h1;
    h0.x = fmaxf(acc[i][0], 0.0f); h0.y = fmaxf(acc[i][1], 0.0f);
    h0.z = fmaxf(acc[i][2], 0.0f); h0.w = fmaxf(acc[i][3], 0.0f);
    h1.x = fmaxf(acc[i][4], 0.0f); h1.y = fmaxf(acc[i][5], 0.0f);
    h1.z = fmaxf(acc[i][6], 0.0f); h1.w = fmaxf(acc[i][7], 0.0f);
    *(float4*)&Zb[wv][2 * tp + i][8 * gs] = h0;
    *(float4*)&Zb[wv][2 * tp + i][8 * gs + 4] = h1;
  }

  // ================= phase B: G = H @ W2 (single 64-k chunk) ==============
  float cb[2][8];
#pragma unroll
  for (int i = 0; i < 2; ++i)
#pragma unroll
    for (int n = 0; n < 8; ++n) cb[i][n] = 0.0f;

#pragma unroll 2
  for (int kq = 0; kq < 16; ++kq) {
    const float4 a0 = *(const float4*)&Zb[wv][2 * tp][4 * kq];
    const float4 a1 = *(const float4*)&Zb[wv][2 * tp + 1][4 * kq];
    const float a0v[4] = {a0.x, a0.y, a0.z, a0.w};
    const float a1v[4] = {a1.x, a1.y, a1.z, a1.w};
    const float* wr = W2 + (long)(4 * kq) * GD_ + 8 * gs;
#pragma unroll
    for (int dk = 0; dk < 4; ++dk) {
      const float4 b0 = *(const float4*)(wr + dk * GD_);
      const float4 b1 = *(const float4*)(wr + dk * GD_ + 4);
      const float bv[8] = {b0.x, b0.y, b0.z, b0.w, b1.x, b1.y, b1.z, b1.w};
#pragma unroll
      for (int n = 0; n < 8; ++n) {
        cb[0][n] = fmaf(a0v[dk], bv[n], cb[0][n]);
        cb[1][n] = fmaf(a1v[dk], bv[n], cb[1][n]);
      }
    }
  }

  // ---- normalize: f64 norms of f32-rounded G, reduce across gs octet
  double ss0 = 0.0, ss1 = 0.0;
#pragma unroll
  for (int n = 0; n < 8; ++n) {
    ss0 += (double)cb[0][n] * (double)cb[0][n];
    ss1 += (double)cb[1][n] * (double)cb[1][n];
  }
#pragma unroll
  for (int m = 1; m < 8; m <<= 1) {
    ss0 += __shfl_xor(ss0, m);
    ss1 += __shfl_xor(ss1, m);
  }
  const double den0 = sqrt(ss0) + 1e-8;
  const double den1 = sqrt(ss1) + 1e-8;

  // g (f32) -> Zb
  {
    float4 g0, g1;
    g0.x = (float)((double)cb[0][0] / den0);
    g0.y = (float)((double)cb[0][1] / den0);
    g0.z = (float)((double)cb[0][2] / den0);
    g0.w = (float)((double)cb[0][3] / den0);
    g1.x = (float)((double)cb[0][4] / den0);
    g1.y = (float)((double)cb[0][5] / den0);
    g1.z = (float)((double)cb[0][6] / den0);
    g1.w = (float)((double)cb[0][7] / den0);
    *(float4*)&Zb[wv][2 * tp][8 * gs] = g0;
    *(float4*)&Zb[wv][2 * tp][8 * gs + 4] = g1;
    g0.x = (float)((double)cb[1][0] / den1);
    g0.y = (float)((double)cb[1][1] / den1);
    g0.z = (float)((double)cb[1][2] / den1);
    g0.w = (float)((double)cb[1][3] / den1);
    g1.x = (float)((double)cb[1][4] / den1);
    g1.y = (float)((double)cb[1][5] / den1);
    g1.z = (float)((double)cb[1][6] / den1);
    g1.w = (float)((double)cb[1][7] / den1);
    *(float4*)&Zb[wv][2 * tp + 1][8 * gs] = g0;
    *(float4*)&Zb[wv][2 * tp + 1][8 * gs + 4] = g1;
  }

  // ---- sims: 15 edges of this wave's window (same-wave DS order: safe)
  if (lane < WSZ_ - 1) {
    const int t = lane;
    double s = 0.0;
#pragma unroll
    for (int q = 0; q < 16; ++q) {
      const float4 a = *(const float4*)&Zb[wv][t][4 * q];
      const float4 b = *(const float4*)&Zb[wv][t + 1][4 * q];
      s += (double)a.x * b.x + (double)a.y * b.y +
           (double)a.z * b.z + (double)a.w * b.w;
    }
    sims_out[((long)blockIdx.x * 4 + wv) * (WSZ_ - 1) + t] = s;
  }
}

// ---------------------------------------------------------------------------
// K2: per-window stable sort + budgeted greedy pick. 1 thread per window.
// ---------------------------------------------------------------------------
__global__ __launch_bounds__(64) void k_pick(
    const double* __restrict__ sims, const int* __restrict__ tlptr,
    int* __restrict__ mrMask, int* __restrict__ keptCnt)
{
  const int win = blockIdx.x * 64 + threadIdx.x;
  if (win >= B_ * NWIN_) return;
  const int w = win % NWIN_;

  const int tl = tlptr[0];
  const int mn = T_ - tl;
  const int base = mn / NWIN_, extra = mn % NWIN_;
  int budget = base + (w < extra ? 1 : 0);
  if (budget > WSZ_ / 2) budget = WSZ_ / 2;
  if (budget < 0) budget = 0;

  double v[WSZ_ - 1];
  int id[WSZ_ - 1];
  for (int e = 0; e < WSZ_ - 1; ++e) {
    v[e] = sims[(long)win * (WSZ_ - 1) + e];
    id[e] = e;
  }
  for (int i = 1; i < WSZ_ - 1; ++i) {
    const double dv = v[i]; const int di = id[i];
    int j = i - 1;
    while (j >= 0 && v[j] < dv) { v[j + 1] = v[j]; id[j + 1] = id[j]; --j; }
    v[j + 1] = dv; id[j + 1] = di;
  }
  bool used[WSZ_];
  for (int i = 0; i < WSZ_; ++i) used[i] = false;
  int mrm = 0, picked = 0;
  for (int ii = 0; ii < WSZ_ - 1; ++ii) {
    const int e = id[ii];
    if (picked < budget && !used[e] && !used[e + 1]) {
      used[e] = used[e + 1] = true;
      mrm |= (1 << (e + 1));
      ++picked;
    }
  }
  mrMask[win] = mrm;
  keptCnt[win] = WSZ_ - picked;
}

// ---------------------------------------------------------------------------
// K3: per-batch exclusive prefix over window kept-counts (tiny)
// ---------------------------------------------------------------------------
__global__ void k_scan_windows(const int* __restrict__ keptCnt,
                               int* __restrict__ outOff)
{
  const int b = threadIdx.x;
  if (b >= B_) return;
  int off = 0;
  for (int w = 0; w < NWIN_; ++w) {
    outOff[b * NWIN_ + w] = off;
    off += keptCnt[b * NWIN_ + w];
  }
}

// ---------------------------------------------------------------------------
// K4: emit z_new rows + lens_new.  grid: B*NWIN blocks, 256 threads.
// ---------------------------------------------------------------------------
__global__ __launch_bounds__(256) void k_emit(
    const float* __restrict__ z, const int* __restrict__ lens,
    const int* __restrict__ mrMask, const int* __restrict__ outOff,
    float* __restrict__ out, int TL)
{
  const int bw = blockIdx.x;
  const int b = bw / NWIN_, w = bw % NWIN_;
  const int tid = threadIdx.x;
  const int mrm = mrMask[bw];
  int p = outOff[bw];
  const int t0 = w * WSZ_;

  const float* zb = z + (long)b * T_ * D_;
  const int* lb = lens + b * T_;
  float* zout = out;
  float* lout = out + (long)B_ * TL * D_;

  for (int i = 0; i < WSZ_; ++i) {
    if ((mrm >> i) & 1) continue;
    if (p >= TL) return;
    const int t = t0 + i;
    const bool ab = (i < WSZ_ - 1) && ((mrm >> (i + 1)) & 1);
    float4 o = *(const float4*)(zb + (long)t * D_ + tid * 4);
    if (ab) {
      const float wi = (float)lb[t], wj = (float)lb[t + 1];
      const float s = wi + wj;
      const float4 zj = *(const float4*)(zb + (long)(t + 1) * D_ + tid * 4);
      o.x = (o.x * wi + zj.x * wj) / s;
      o.y = (o.y * wi + zj.y * wj) / s;
      o.z = (o.z * wi + zj.z * wj) / s;
      o.w = (o.w * wi + zj.w * wj) / s;
      if (tid == 0) lout[(long)b * TL + p] = s;
    } else {
      if (tid == 0) lout[(long)b * TL + p] = (float)lb[t];
    }
    *(float4*)(zout + ((long)b * TL + p) * D_ + tid * 4) = o;
    ++p;
  }
}

// ---------------------------------------------------------------------------
// K5: starts = exclusive cumsum of lens_new per row. grid: B blocks, 256 thr.
// ---------------------------------------------------------------------------
__global__ __launch_bounds__(256) void k_starts(
    const float* __restrict__ lens_f, float* __restrict__ starts, int TL)
{
  const int b = blockIdx.x;
  const int tid = threadIdx.x;
  const int lane = tid & 63, wv = tid >> 6;
  __shared__ float wsum[4];
  const float* lrow = lens_f + (long)b * TL;
  float* srow = starts + (long)b * TL;
  float carry = 0.0f;

  for (int c0 = 0; c0 < TL; c0 += 256) {
    const int j = c0 + tid;
    const float v = (j < TL) ? lrow[j] : 0.0f;
    float x = v;
#pragma unroll
    for (int d = 1; d < 64; d <<= 1) {
      const float o = __shfl_up(x, d);
      if (lane >= d) x += o;
    }
    if (lane == 63) wsum[wv] = x;
    __syncthreads();
    float pre = 0.0f;
    if (wv > 0) pre += wsum[0];
    if (wv > 1) pre += wsum[1];
    if (wv > 2) pre += wsum[2];
    const float tot = wsum[0] + wsum[1] + wsum[2] + wsum[3];
    if (j < TL) srow[j] = carry + pre + x - v;
    carry += tot;
    __syncthreads();
  }
}

// ---------------------------------------------------------------------------
extern "C" void kernel_launch(void* const* d_in, const int* in_sizes, int n_in,
                              void* d_out, int out_size, void* d_ws, size_t ws_size,
                              hipStream_t stream)
{
  const float* z    = (const float*)d_in[0];
  const int*   lens = (const int*)d_in[1];
  const float* W1   = (const float*)d_in[2];
  const float* W2   = (const float*)d_in[3];
  const int*   tlp  = (const int*)d_in[4];

  float* out = (float*)d_out;
  const int TL = out_size / (B_ * (D_ + 2));   // 6144

  double* sims  = (double*)d_ws;
  int* mrMask = (int*)((char*)d_ws + (size_t)B_ * NWIN_ * (WSZ_ - 1) * 8);
  int* kept   = mrMask + B_ * NWIN_;
  int* outOff = kept + B_ * NWIN_;

  hipLaunchKernelGGL(k_sims, dim3((B_ * T_) / 64), dim3(256), 0, stream,
                     z, W1, W2, sims);
  hipLaunchKernelGGL(k_pick, dim3((B_ * NWIN_ + 63) / 64), dim3(64), 0, stream,
                     sims, tlp, mrMask, kept);
  hipLaunchKernelGGL(k_scan_windows, dim3(1), dim3(64), 0, stream,
                     kept, outOff);
  hipLaunchKernelGGL(k_emit, dim3(B_ * NWIN_), dim3(256), 0, stream,
                     z, lens, mrMask, outOff, out, TL);
  hipLaunchKernelGGL(k_starts, dim3(B_), dim3(256), 0, stream,
                     out + (long)B_ * TL * D_,
                     out + (long)B_ * TL * D_ + (long)B_ * TL, TL);
}

// Round 7
// 460.347 us; speedup vs baseline: 1.0455x; 1.0455x over previous
//
#include <hip/hip_runtime.h>

#define B_ 8
#define T_ 8192
#define D_ 1024
#define GD_ 64
#define WSZ_ 16
#define NWIN_ (T_ / WSZ_)   // 512

// Raw barrier: waits only LDS ops, leaves prefetch global loads in flight
// (avoids the compiler's conservative vmcnt(0) drain at __syncthreads).
#define BARRIER()                                            \
  do {                                                       \
    asm volatile("s_waitcnt lgkmcnt(0)" ::: "memory");       \
    __builtin_amdgcn_s_barrier();                            \
  } while (0)

// ---------------------------------------------------------------------------
// K1 (fused): sims of g = normalize(relu(z@W1)@W2).
// R4 structure (64 tok x 64 gd, 4 waves, K split 4-way across waves,
// single-buffered LDS) + register prefetch of the next chunk (z and W1)
// issued right after barrier-1 so HBM latency hides under compute.
// Numeric path identical to validated R4: f32 FMA per 16-k wave slice,
// f32 chunk->total accumulation, cross-wave pairwise f32 tree, f64
// norms and sims -> picks identical.
// ---------------------------------------------------------------------------
__global__ __launch_bounds__(256) void k_sims(
    const float* __restrict__ z, const float* __restrict__ W1,
    const float* __restrict__ W2, double* __restrict__ sims_out)
{
  __shared__ float Zs[64][64];   // z chunk / scratch / H / G  (^(row>>3)&7)
  __shared__ float Ws[64][64];   // W1 chunk / scratch / W2    (^(row>>1)&7)

  const int tid = threadIdx.x;
  const int w = tid >> 6;        // wave 0..3
  const int lane = tid & 63;
  const int ts = lane >> 3;      // token octet
  const int gs = lane & 7;       // gd octet
  const int q = gs & 1;
  const long bt0 = (long)blockIdx.x * 64;
  const int rb0 = 8 * ts + 4 * q;
  const int rb1 = 8 * ts + 4 - 4 * q;

  // staging map: reg j <-> row = 16*j + (tid>>4), col quad = tid&15
  const int srow = tid >> 4;
  const int sc4 = tid & 15;

  auto commit = [&](float4 (&zr)[4], float4 (&wr)[4]) {
#pragma unroll
    for (int j = 0; j < 4; ++j) {
      const int row = 16 * j + srow;
      *(float4*)&Zs[row][4 * (sc4 ^ ((row >> 3) & 7))] = zr[j];
      *(float4*)&Ws[row][4 * (sc4 ^ ((row >> 1) & 7))] = wr[j];
    }
  };

  auto partWrite = [&](float (*Ls)[64], float (&A)[8][8]) {
#pragma unroll
    for (int m = 0; m < 8; ++m) {
      const int row = (m < 4) ? (rb0 + m) : (rb1 + m - 4);
      *(float4*)&Ls[row][4 * ((2 * gs) ^ ts)] =
          make_float4(A[m][0], A[m][1], A[m][2], A[m][3]);
      *(float4*)&Ls[row][4 * ((2 * gs + 1) ^ ts)] =
          make_float4(A[m][4], A[m][5], A[m][6], A[m][7]);
    }
  };
  auto partAdd = [&](float (*Ls)[64], float (&A)[8][8]) {
#pragma unroll
    for (int m = 0; m < 8; ++m) {
      const int row = (m < 4) ? (rb0 + m) : (rb1 + m - 4);
      const float4 v0 = *(const float4*)&Ls[row][4 * ((2 * gs) ^ ts)];
      const float4 v1 = *(const float4*)&Ls[row][4 * ((2 * gs + 1) ^ ts)];
      A[m][0] += v0.x; A[m][1] += v0.y; A[m][2] += v0.z; A[m][3] += v0.w;
      A[m][4] += v1.x; A[m][5] += v1.y; A[m][6] += v1.z; A[m][7] += v1.w;
    }
  };

  auto step4 = [&](float (*As)[64], float (*Bs)[64], int kk,
                   float (&C)[8][8]) {
    const int c4k = kk >> 2;
    float A8[8][4];
#pragma unroll
    for (int m = 0; m < 4; ++m) {
      const float4 o = *(const float4*)&As[rb0 + m][4 * (c4k ^ ts)];
      A8[m][0] = o.x; A8[m][1] = o.y; A8[m][2] = o.z; A8[m][3] = o.w;
      A8[m + 4][0] = __shfl_xor(o.x, 1);
      A8[m + 4][1] = __shfl_xor(o.y, 1);
      A8[m + 4][2] = __shfl_xor(o.z, 1);
      A8[m + 4][3] = __shfl_xor(o.w, 1);
    }
    float bv[4][8];
#pragma unroll
    for (int jk = 0; jk < 4; ++jk) {
      const int kr = kk + jk;
      const int sw = (kr >> 1) & 7;
      const float4 b0 = *(const float4*)&Bs[kr][4 * ((2 * gs) ^ sw)];
      const float4 b1 = *(const float4*)&Bs[kr][4 * ((2 * gs + 1) ^ sw)];
      bv[jk][0] = b0.x; bv[jk][1] = b0.y; bv[jk][2] = b0.z; bv[jk][3] = b0.w;
      bv[jk][4] = b1.x; bv[jk][5] = b1.y; bv[jk][6] = b1.z; bv[jk][7] = b1.w;
    }
#pragma unroll
    for (int jk = 0; jk < 4; ++jk)
#pragma unroll
      for (int m = 0; m < 8; ++m)
#pragma unroll
        for (int n = 0; n < 8; ++n)
          C[m][n] = fmaf(A8[m][jk], bv[jk][n], C[m][n]);
  };

  float acc[8][8];
#pragma unroll
  for (int m = 0; m < 8; ++m)
#pragma unroll
    for (int n = 0; n < 8; ++n) acc[m][n] = 0.0f;

  // ---- initial prefetch (chunk 0)
  float4 zr[4], wr[4];
#pragma unroll
  for (int j = 0; j < 4; ++j) {
    const int row = 16 * j + srow;
    zr[j] = *(const float4*)(z + (bt0 + row) * D_ + 4 * sc4);
    wr[j] = *(const float4*)(W1 + (long)row * GD_ + 4 * sc4);
  }

  // ================= phase A: H = z @ W1 ==================================
#pragma unroll 1
  for (int c = 0; c < 16; ++c) {
    commit(zr, wr);               // ds_write (waits vmcnt on zr/wr)
    BARRIER();                    // writes visible; prefetch stays in flight
    if (c < 15) {                 // issue prefetch for c+1 (hides under FMA)
#pragma unroll
      for (int j = 0; j < 4; ++j) {
        const int row = 16 * j + srow;
        zr[j] = *(const float4*)(z + (bt0 + row) * D_ + (c + 1) * 64 + 4 * sc4);
        wr[j] = *(const float4*)(W1 + (long)((c + 1) * 64 + row) * GD_ + 4 * sc4);
      }
    }
    float cacc[8][8];
#pragma unroll
    for (int m = 0; m < 8; ++m)
#pragma unroll
      for (int n = 0; n < 8; ++n) cacc[m][n] = 0.0f;
#pragma unroll
    for (int ii = 0; ii < 4; ++ii)
      step4(Zs, Ws, 16 * w + 4 * ii, cacc);
#pragma unroll
    for (int m = 0; m < 8; ++m)
#pragma unroll
      for (int n = 0; n < 8; ++n) acc[m][n] += cacc[m][n];
    BARRIER();                    // all reads of chunk c consumed
  }

  // ---- cross-wave reduce of H partials ((w0+w2)+(w1+w3)), scratch Zs/Ws
  if (w == 2) partWrite(Zs, acc);
  if (w == 3) partWrite(Ws, acc);
  BARRIER();
  if (w == 0) partAdd(Zs, acc);
  if (w == 1) partAdd(Ws, acc);
  BARRIER();
  if (w == 1) partWrite(Zs, acc);
  BARRIER();
  if (w == 0) {
    partAdd(Zs, acc);
#pragma unroll
    for (int m = 0; m < 8; ++m)
#pragma unroll
      for (int n = 0; n < 8; ++n) acc[m][n] = fmaxf(acc[m][n], 0.0f);
    partWrite(Zs, acc);           // H -> Zs
  }
  // stage W2 into Ws (16 KB, L2-hot; Ws reads finished 2 barriers ago)
#pragma unroll
  for (int j = 0; j < 4; ++j) {
    const int row = 16 * j + srow;
    *(float4*)&Ws[row][4 * (sc4 ^ ((row >> 1) & 7))] =
        *(const float4*)(W2 + (long)row * GD_ + 4 * sc4);
  }
  BARRIER();

  // ================= phase B: G = H @ W2 ==================================
  float cb[8][8];
#pragma unroll
  for (int m = 0; m < 8; ++m)
#pragma unroll
    for (int n = 0; n < 8; ++n) cb[m][n] = 0.0f;
#pragma unroll
  for (int ii = 0; ii < 4; ++ii)
    step4(Zs, Ws, 16 * w + 4 * ii, cb);
  BARRIER();                      // all H/W2 reads done

  if (w == 2) partWrite(Zs, cb);
  if (w == 3) partWrite(Ws, cb);
  BARRIER();
  if (w == 0) partAdd(Zs, cb);
  if (w == 1) partAdd(Ws, cb);
  BARRIER();
  if (w == 1) partWrite(Zs, cb);
  BARRIER();
  if (w == 0) {
    partAdd(Zs, cb);
    partWrite(Zs, cb);            // raw G -> Zs
  }
  BARRIER();

  // ---- norms (f64) of G rows; den in Ws scratch; then sims (wave 0 only)
  double* den = (double*)&Ws[0][0];
  if (tid < 64) {
    const int t = tid;
    const int swt = (t >> 3) & 7;
    double ss = 0.0;
#pragma unroll
    for (int c4 = 0; c4 < 16; ++c4) {
      const float4 v = *(const float4*)&Zs[t][4 * (c4 ^ swt)];
      ss += (double)v.x * v.x + (double)v.y * v.y +
            (double)v.z * v.z + (double)v.w * v.w;
    }
    den[t] = sqrt(ss) + 1e-8;
  }
  // same wave computes sims; same-wave DS ordering -> no barrier needed
  if (tid < 4 * (WSZ_ - 1)) {
    const int ww = tid / (WSZ_ - 1), e = tid % (WSZ_ - 1);
    const int t = ww * WSZ_ + e;
    const int swa = (t >> 3) & 7, swb = ((t + 1) >> 3) & 7;
    double s = 0.0;
#pragma unroll
    for (int c4 = 0; c4 < 16; ++c4) {
      const float4 a = *(const float4*)&Zs[t][4 * (c4 ^ swa)];
      const float4 b = *(const float4*)&Zs[t + 1][4 * (c4 ^ swb)];
      s += (double)a.x * b.x + (double)a.y * b.y +
           (double)a.z * b.z + (double)a.w * b.w;
    }
    sims_out[((long)blockIdx.x * 4 + ww) * (WSZ_ - 1) + e] =
        s / (den[t] * den[t + 1]);
  }
}

// ---------------------------------------------------------------------------
// K2: per-window stable sort + budgeted greedy pick. 1 thread per window.
// ---------------------------------------------------------------------------
__global__ __launch_bounds__(64) void k_pick(
    const double* __restrict__ sims, const int* __restrict__ tlptr,
    int* __restrict__ mrMask, int* __restrict__ keptCnt)
{
  const int win = blockIdx.x * 64 + threadIdx.x;
  if (win >= B_ * NWIN_) return;
  const int w = win % NWIN_;

  const int tl = tlptr[0];
  const int mn = T_ - tl;
  const int base = mn / NWIN_, extra = mn % NWIN_;
  int budget = base + (w < extra ? 1 : 0);
  if (budget > WSZ_ / 2) budget = WSZ_ / 2;
  if (budget < 0) budget = 0;

  double v[WSZ_ - 1];
  int id[WSZ_ - 1];
  for (int e = 0; e < WSZ_ - 1; ++e) {
    v[e] = sims[(long)win * (WSZ_ - 1) + e];
    id[e] = e;
  }
  for (int i = 1; i < WSZ_ - 1; ++i) {
    const double dv = v[i]; const int di = id[i];
    int j = i - 1;
    while (j >= 0 && v[j] < dv) { v[j + 1] = v[j]; id[j + 1] = id[j]; --j; }
    v[j + 1] = dv; id[j + 1] = di;
  }
  bool used[WSZ_];
  for (int i = 0; i < WSZ_; ++i) used[i] = false;
  int mrm = 0, picked = 0;
  for (int ii = 0; ii < WSZ_ - 1; ++ii) {
    const int e = id[ii];
    if (picked < budget && !used[e] && !used[e + 1]) {
      used[e] = used[e + 1] = true;
      mrm |= (1 << (e + 1));
      ++picked;
    }
  }
  mrMask[win] = mrm;
  keptCnt[win] = WSZ_ - picked;
}

// ---------------------------------------------------------------------------
// K3: per-batch exclusive prefix over window kept-counts (tiny)
// ---------------------------------------------------------------------------
__global__ void k_scan_windows(const int* __restrict__ keptCnt,
                               int* __restrict__ outOff)
{
  const int b = threadIdx.x;
  if (b >= B_) return;
  int off = 0;
  for (int w = 0; w < NWIN_; ++w) {
    outOff[b * NWIN_ + w] = off;
    off += keptCnt[b * NWIN_ + w];
  }
}

// ---------------------------------------------------------------------------
// K4: emit z_new rows + lens_new.  grid: B*NWIN blocks, 256 threads.
// ---------------------------------------------------------------------------
__global__ __launch_bounds__(256) void k_emit(
    const float* __restrict__ z, const int* __restrict__ lens,
    const int* __restrict__ mrMask, const int* __restrict__ outOff,
    float* __restrict__ out, int TL)
{
  const int bw = blockIdx.x;
  const int b = bw / NWIN_, w = bw % NWIN_;
  const int tid = threadIdx.x;
  const int mrm = mrMask[bw];
  int p = outOff[bw];
  const int t0 = w * WSZ_;

  const float* zb = z + (long)b * T_ * D_;
  const int* lb = lens + b * T_;
  float* zout = out;
  float* lout = out + (long)B_ * TL * D_;

  for (int i = 0; i < WSZ_; ++i) {
    if ((mrm >> i) & 1) continue;
    if (p >= TL) return;
    const int t = t0 + i;
    const bool ab = (i < WSZ_ - 1) && ((mrm >> (i + 1)) & 1);
    float4 o = *(const float4*)(zb + (long)t * D_ + tid * 4);
    if (ab) {
      const float wi = (float)lb[t], wj = (float)lb[t + 1];
      const float s = wi + wj;
      const float4 zj = *(const float4*)(zb + (long)(t + 1) * D_ + tid * 4);
      o.x = (o.x * wi + zj.x * wj) / s;
      o.y = (o.y * wi + zj.y * wj) / s;
      o.z = (o.z * wi + zj.z * wj) / s;
      o.w = (o.w * wi + zj.w * wj) / s;
      if (tid == 0) lout[(long)b * TL + p] = s;
    } else {
      if (tid == 0) lout[(long)b * TL + p] = (float)lb[t];
    }
    *(float4*)(zout + ((long)b * TL + p) * D_ + tid * 4) = o;
    ++p;
  }
}

// ---------------------------------------------------------------------------
// K5: starts = exclusive cumsum of lens_new per row. grid: B blocks, 256 thr.
// ---------------------------------------------------------------------------
__global__ __launch_bounds__(256) void k_starts(
    const float* __restrict__ lens_f, float* __restrict__ starts, int TL)
{
  const int b = blockIdx.x;
  const int tid = threadIdx.x;
  const int lane = tid & 63, wv = tid >> 6;
  __shared__ float wsum[4];
  const float* lrow = lens_f + (long)b * TL;
  float* srow = starts + (long)b * TL;
  float carry = 0.0f;

  for (int c0 = 0; c0 < TL; c0 += 256) {
    const int j = c0 + tid;
    const float v = (j < TL) ? lrow[j] : 0.0f;
    float x = v;
#pragma unroll
    for (int d = 1; d < 64; d <<= 1) {
      const float o = __shfl_up(x, d);
      if (lane >= d) x += o;
    }
    if (lane == 63) wsum[wv] = x;
    __syncthreads();
    float pre = 0.0f;
    if (wv > 0) pre += wsum[0];
    if (wv > 1) pre += wsum[1];
    if (wv > 2) pre += wsum[2];
    const float tot = wsum[0] + wsum[1] + wsum[2] + wsum[3];
    if (j < TL) srow[j] = carry + pre + x - v;
    carry += tot;
    __syncthreads();
  }
}

// ---------------------------------------------------------------------------
extern "C" void kernel_launch(void* const* d_in, const int* in_sizes, int n_in,
                              void* d_out, int out_size, void* d_ws, size_t ws_size,
                              hipStream_t stream)
{
  const float* z    = (const float*)d_in[0];
  const int*   lens = (const int*)d_in[1];
  const float* W1   = (const float*)d_in[2];
  const float* W2   = (const float*)d_in[3];
  const int*   tlp  = (const int*)d_in[4];

  float* out = (float*)d_out;
  const int TL = out_size / (B_ * (D_ + 2));   // 6144

  double* sims  = (double*)d_ws;
  int* mrMask = (int*)((char*)d_ws + (size_t)B_ * NWIN_ * (WSZ_ - 1) * 8);
  int* kept   = mrMask + B_ * NWIN_;
  int* outOff = kept + B_ * NWIN_;

  hipLaunchKernelGGL(k_sims, dim3((B_ * T_) / 64), dim3(256), 0, stream,
                     z, W1, W2, sims);
  hipLaunchKernelGGL(k_pick, dim3((B_ * NWIN_ + 63) / 64), dim3(64), 0, stream,
                     sims, tlp, mrMask, kept);
  hipLaunchKernelGGL(k_scan_windows, dim3(1), dim3(64), 0, stream,
                     kept, outOff);
  hipLaunchKernelGGL(k_emit, dim3(B_ * NWIN_), dim3(256), 0, stream,
                     z, lens, mrMask, outOff, out, TL);
  hipLaunchKernelGGL(k_starts, dim3(B_), dim3(256), 0, stream,
                     out + (long)B_ * TL * D_,
                     out + (long)B_ * TL * D_ + (long)B_ * TL, TL);
}

// Round 8
// 251.028 us; speedup vs baseline: 1.9173x; 1.8338x over previous
//
#include <hip/hip_runtime.h>

#define B_ 8
#define T_ 8192
#define D_ 1024
#define GD_ 64
#define WSZ_ 16
#define NWIN_ (T_ / WSZ_)   // 512

// ---------------------------------------------------------------------------
// K1 (fused): sims of g = normalize(relu(z@W1)@W2).
// R4 structure (validated, 182us): 64 tok x 64 gd, 256 thr = 4 waves, K
// split 4-way across waves, single-buffered LDS, plain __syncthreads.
// Change vs R4: step4 reads A directly (8 ds_read_b128) instead of
// 4 reads + 16 __shfl_xor (shfl = ds_swizzle = LDS pipe) -> ~19% fewer
// LDS cycles and fewer VALU issues, no extra register pressure.
// Numeric path: f32 FMA per 16-k wave slice, f32 chunk->total, cross-wave
// pairwise f32 tree, f64 norms and sims (validated class, zero pick flips).
// ---------------------------------------------------------------------------
__global__ __launch_bounds__(256) void k_sims(
    const float* __restrict__ z, const float* __restrict__ W1,
    const float* __restrict__ W2, double* __restrict__ sims_out)
{
  __shared__ float Zs[64][64];   // z chunk / scratch / H / G  (^(row>>3)&7)
  __shared__ float Ws[64][64];   // W1 chunk / scratch / W2    (^(row>>1)&7)

  const int tid = threadIdx.x;
  const int w = tid >> 6;        // wave 0..3
  const int lane = tid & 63;
  const int ts = lane >> 3;      // token octet: rows 8ts..8ts+7
  const int gs = lane & 7;       // gd octet:   cols 8gs..8gs+7
  const long bt0 = (long)blockIdx.x * 64;

  // staging map: reg j <-> row = 16*j + (tid>>4), col quad = tid&15
  const int srow = tid >> 4;
  const int sc4 = tid & 15;

  auto partWrite = [&](float (*Ls)[64], float (&A)[8][8]) {
#pragma unroll
    for (int m = 0; m < 8; ++m) {
      const int row = 8 * ts + m;
      *(float4*)&Ls[row][4 * ((2 * gs) ^ ts)] =
          make_float4(A[m][0], A[m][1], A[m][2], A[m][3]);
      *(float4*)&Ls[row][4 * ((2 * gs + 1) ^ ts)] =
          make_float4(A[m][4], A[m][5], A[m][6], A[m][7]);
    }
  };
  auto partAdd = [&](float (*Ls)[64], float (&A)[8][8]) {
#pragma unroll
    for (int m = 0; m < 8; ++m) {
      const int row = 8 * ts + m;
      const float4 v0 = *(const float4*)&Ls[row][4 * ((2 * gs) ^ ts)];
      const float4 v1 = *(const float4*)&Ls[row][4 * ((2 * gs + 1) ^ ts)];
      A[m][0] += v0.x; A[m][1] += v0.y; A[m][2] += v0.z; A[m][3] += v0.w;
      A[m][4] += v1.x; A[m][5] += v1.y; A[m][6] += v1.z; A[m][7] += v1.w;
    }
  };

  // inner 4k step: A 8 b128 (direct), B 8 b128, 256 FMA
  auto step4 = [&](float (*As)[64], float (*Bs)[64], int kk,
                   float (&C)[8][8]) {
    const int c4k = kk >> 2;
    float A8[8][4];
#pragma unroll
    for (int m = 0; m < 8; ++m) {
      const float4 o = *(const float4*)&As[8 * ts + m][4 * (c4k ^ ts)];
      A8[m][0] = o.x; A8[m][1] = o.y; A8[m][2] = o.z; A8[m][3] = o.w;
    }
#pragma unroll
    for (int jk = 0; jk < 4; ++jk) {
      const int kr = kk + jk;
      const int sw = (kr >> 1) & 7;
      const float4 b0 = *(const float4*)&Bs[kr][4 * ((2 * gs) ^ sw)];
      const float4 b1 = *(const float4*)&Bs[kr][4 * ((2 * gs + 1) ^ sw)];
      const float bv[8] = {b0.x, b0.y, b0.z, b0.w, b1.x, b1.y, b1.z, b1.w};
#pragma unroll
      for (int m = 0; m < 8; ++m)
#pragma unroll
        for (int n = 0; n < 8; ++n)
          C[m][n] = fmaf(A8[m][jk], bv[n], C[m][n]);
    }
  };

  float acc[8][8];
#pragma unroll
  for (int m = 0; m < 8; ++m)
#pragma unroll
    for (int n = 0; n < 8; ++n) acc[m][n] = 0.0f;

  // ================= phase A: H = z @ W1 ==================================
#pragma unroll 1
  for (int c = 0; c < 16; ++c) {
    const int k0 = c * 64;
    if (c) __syncthreads();
    // stage z chunk + W1 chunk (coalesced b128 both ways, XOR-swizzled)
#pragma unroll
    for (int j = 0; j < 4; ++j) {
      const int row = 16 * j + srow;
      const float4 v = *(const float4*)(z + (bt0 + row) * D_ + k0 + 4 * sc4);
      *(float4*)&Zs[row][4 * (sc4 ^ ((row >> 3) & 7))] = v;
      const float4 u = *(const float4*)(W1 + (long)(k0 + row) * GD_ + 4 * sc4);
      *(float4*)&Ws[row][4 * (sc4 ^ ((row >> 1) & 7))] = u;
    }
    __syncthreads();
    float cacc[8][8];
#pragma unroll
    for (int m = 0; m < 8; ++m)
#pragma unroll
      for (int n = 0; n < 8; ++n) cacc[m][n] = 0.0f;
#pragma unroll
    for (int ii = 0; ii < 4; ++ii)
      step4(Zs, Ws, 16 * w + 4 * ii, cacc);
#pragma unroll
    for (int m = 0; m < 8; ++m)
#pragma unroll
      for (int n = 0; n < 8; ++n) acc[m][n] += cacc[m][n];
  }
  __syncthreads();

  // ---- cross-wave reduce of H partials ((w0+w2)+(w1+w3)), scratch Zs/Ws
  if (w == 2) partWrite(Zs, acc);
  if (w == 3) partWrite(Ws, acc);
  __syncthreads();
  if (w == 0) partAdd(Zs, acc);
  if (w == 1) partAdd(Ws, acc);
  __syncthreads();
  if (w == 1) partWrite(Zs, acc);
  __syncthreads();
  if (w == 0) {
    partAdd(Zs, acc);
#pragma unroll
    for (int m = 0; m < 8; ++m)
#pragma unroll
      for (int n = 0; n < 8; ++n) acc[m][n] = fmaxf(acc[m][n], 0.0f);
    partWrite(Zs, acc);           // H -> Zs
  }
  // stage W2 into Ws (Ws reads finished 2 barriers ago)
#pragma unroll
  for (int j = 0; j < 4; ++j) {
    const int row = 16 * j + srow;
    *(float4*)&Ws[row][4 * (sc4 ^ ((row >> 1) & 7))] =
        *(const float4*)(W2 + (long)row * GD_ + 4 * sc4);
  }
  __syncthreads();

  // ================= phase B: G = H @ W2 ==================================
  float cb[8][8];
#pragma unroll
  for (int m = 0; m < 8; ++m)
#pragma unroll
    for (int n = 0; n < 8; ++n) cb[m][n] = 0.0f;
#pragma unroll
  for (int ii = 0; ii < 4; ++ii)
    step4(Zs, Ws, 16 * w + 4 * ii, cb);
  __syncthreads();

  if (w == 2) partWrite(Zs, cb);
  if (w == 3) partWrite(Ws, cb);
  __syncthreads();
  if (w == 0) partAdd(Zs, cb);
  if (w == 1) partAdd(Ws, cb);
  __syncthreads();
  if (w == 1) partWrite(Zs, cb);
  __syncthreads();
  if (w == 0) {
    partAdd(Zs, cb);
    partWrite(Zs, cb);            // raw G -> Zs
  }
  __syncthreads();

  // ---- norms (f64) of G rows; den in Ws scratch; sims by wave 0
  double* den = (double*)&Ws[0][0];
  if (tid < 64) {
    const int t = tid;
    const int swt = (t >> 3) & 7;
    double ss = 0.0;
#pragma unroll
    for (int c4 = 0; c4 < 16; ++c4) {
      const float4 v = *(const float4*)&Zs[t][4 * (c4 ^ swt)];
      ss += (double)v.x * v.x + (double)v.y * v.y +
            (double)v.z * v.z + (double)v.w * v.w;
    }
    den[t] = sqrt(ss) + 1e-8;
  }
  if (tid < 4 * (WSZ_ - 1)) {
    const int ww = tid / (WSZ_ - 1), e = tid % (WSZ_ - 1);
    const int t = ww * WSZ_ + e;
    const int swa = (t >> 3) & 7, swb = ((t + 1) >> 3) & 7;
    double s = 0.0;
#pragma unroll
    for (int c4 = 0; c4 < 16; ++c4) {
      const float4 a = *(const float4*)&Zs[t][4 * (c4 ^ swa)];
      const float4 b = *(const float4*)&Zs[t + 1][4 * (c4 ^ swb)];
      s += (double)a.x * b.x + (double)a.y * b.y +
           (double)a.z * b.z + (double)a.w * b.w;
    }
    sims_out[((long)blockIdx.x * 4 + ww) * (WSZ_ - 1) + e] =
        s / (den[t] * den[t + 1]);
  }
}

// ---------------------------------------------------------------------------
// K2: per-window stable sort + budgeted greedy pick. 1 thread per window.
// ---------------------------------------------------------------------------
__global__ __launch_bounds__(64) void k_pick(
    const double* __restrict__ sims, const int* __restrict__ tlptr,
    int* __restrict__ mrMask, int* __restrict__ keptCnt)
{
  const int win = blockIdx.x * 64 + threadIdx.x;
  if (win >= B_ * NWIN_) return;
  const int w = win % NWIN_;

  const int tl = tlptr[0];
  const int mn = T_ - tl;
  const int base = mn / NWIN_, extra = mn % NWIN_;
  int budget = base + (w < extra ? 1 : 0);
  if (budget > WSZ_ / 2) budget = WSZ_ / 2;
  if (budget < 0) budget = 0;

  double v[WSZ_ - 1];
  int id[WSZ_ - 1];
  for (int e = 0; e < WSZ_ - 1; ++e) {
    v[e] = sims[(long)win * (WSZ_ - 1) + e];
    id[e] = e;
  }
  for (int i = 1; i < WSZ_ - 1; ++i) {
    const double dv = v[i]; const int di = id[i];
    int j = i - 1;
    while (j >= 0 && v[j] < dv) { v[j + 1] = v[j]; id[j + 1] = id[j]; --j; }
    v[j + 1] = dv; id[j + 1] = di;
  }
  bool used[WSZ_];
  for (int i = 0; i < WSZ_; ++i) used[i] = false;
  int mrm = 0, picked = 0;
  for (int ii = 0; ii < WSZ_ - 1; ++ii) {
    const int e = id[ii];
    if (picked < budget && !used[e] && !used[e + 1]) {
      used[e] = used[e + 1] = true;
      mrm |= (1 << (e + 1));
      ++picked;
    }
  }
  mrMask[win] = mrm;
  keptCnt[win] = WSZ_ - picked;
}

// ---------------------------------------------------------------------------
// K3: per-batch exclusive prefix over window kept-counts (tiny)
// ---------------------------------------------------------------------------
__global__ void k_scan_windows(const int* __restrict__ keptCnt,
                               int* __restrict__ outOff)
{
  const int b = threadIdx.x;
  if (b >= B_) return;
  int off = 0;
  for (int w = 0; w < NWIN_; ++w) {
    outOff[b * NWIN_ + w] = off;
    off += keptCnt[b * NWIN_ + w];
  }
}

// ---------------------------------------------------------------------------
// K4: emit z_new rows + lens_new.  grid: B*NWIN blocks, 256 threads.
// ---------------------------------------------------------------------------
__global__ __launch_bounds__(256) void k_emit(
    const float* __restrict__ z, const int* __restrict__ lens,
    const int* __restrict__ mrMask, const int* __restrict__ outOff,
    float* __restrict__ out, int TL)
{
  const int bw = blockIdx.x;
  const int b = bw / NWIN_, w = bw % NWIN_;
  const int tid = threadIdx.x;
  const int mrm = mrMask[bw];
  int p = outOff[bw];
  const int t0 = w * WSZ_;

  const float* zb = z + (long)b * T_ * D_;
  const int* lb = lens + b * T_;
  float* zout = out;
  float* lout = out + (long)B_ * TL * D_;

  for (int i = 0; i < WSZ_; ++i) {
    if ((mrm >> i) & 1) continue;
    if (p >= TL) return;
    const int t = t0 + i;
    const bool ab = (i < WSZ_ - 1) && ((mrm >> (i + 1)) & 1);
    float4 o = *(const float4*)(zb + (long)t * D_ + tid * 4);
    if (ab) {
      const float wi = (float)lb[t], wj = (float)lb[t + 1];
      const float s = wi + wj;
      const float4 zj = *(const float4*)(zb + (long)(t + 1) * D_ + tid * 4);
      o.x = (o.x * wi + zj.x * wj) / s;
      o.y = (o.y * wi + zj.y * wj) / s;
      o.z = (o.z * wi + zj.z * wj) / s;
      o.w = (o.w * wi + zj.w * wj) / s;
      if (tid == 0) lout[(long)b * TL + p] = s;
    } else {
      if (tid == 0) lout[(long)b * TL + p] = (float)lb[t];
    }
    *(float4*)(zout + ((long)b * TL + p) * D_ + tid * 4) = o;
    ++p;
  }
}

// ---------------------------------------------------------------------------
// K5: starts = exclusive cumsum of lens_new per row. grid: B blocks, 256 thr.
// ---------------------------------------------------------------------------
__global__ __launch_bounds__(256) void k_starts(
    const float* __restrict__ lens_f, float* __restrict__ starts, int TL)
{
  const int b = blockIdx.x;
  const int tid = threadIdx.x;
  const int lane = tid & 63, wv = tid >> 6;
  __shared__ float wsum[4];
  const float* lrow = lens_f + (long)b * TL;
  float* srow = starts + (long)b * TL;
  float carry = 0.0f;

  for (int c0 = 0; c0 < TL; c0 += 256) {
    const int j = c0 + tid;
    const float v = (j < TL) ? lrow[j] : 0.0f;
    float x = v;
#pragma unroll
    for (int d = 1; d < 64; d <<= 1) {
      const float o = __shfl_up(x, d);
      if (lane >= d) x += o;
    }
    if (lane == 63) wsum[wv] = x;
    __syncthreads();
    float pre = 0.0f;
    if (wv > 0) pre += wsum[0];
    if (wv > 1) pre += wsum[1];
    if (wv > 2) pre += wsum[2];
    const float tot = wsum[0] + wsum[1] + wsum[2] + wsum[3];
    if (j < TL) srow[j] = carry + pre + x - v;
    carry += tot;
    __syncthreads();
  }
}

// ---------------------------------------------------------------------------
extern "C" void kernel_launch(void* const* d_in, const int* in_sizes, int n_in,
                              void* d_out, int out_size, void* d_ws, size_t ws_size,
                              hipStream_t stream)
{
  const float* z    = (const float*)d_in[0];
  const int*   lens = (const int*)d_in[1];
  const float* W1   = (const float*)d_in[2];
  const float* W2   = (const float*)d_in[3];
  const int*   tlp  = (const int*)d_in[4];

  float* out = (float*)d_out;
  const int TL = out_size / (B_ * (D_ + 2));   // 6144

  double* sims  = (double*)d_ws;
  int* mrMask = (int*)((char*)d_ws + (size_t)B_ * NWIN_ * (WSZ_ - 1) * 8);
  int* kept   = mrMask + B_ * NWIN_;
  int* outOff = kept + B_ * NWIN_;

  hipLaunchKernelGGL(k_sims, dim3((B_ * T_) / 64), dim3(256), 0, stream,
                     z, W1, W2, sims);
  hipLaunchKernelGGL(k_pick, dim3((B_ * NWIN_ + 63) / 64), dim3(64), 0, stream,
                     sims, tlp, mrMask, kept);
  hipLaunchKernelGGL(k_scan_windows, dim3(1), dim3(64), 0, stream,
                     kept, outOff);
  hipLaunchKernelGGL(k_emit, dim3(B_ * NWIN_), dim3(256), 0, stream,
                     z, lens, mrMask, outOff, out, TL);
  hipLaunchKernelGGL(k_starts, dim3(B_), dim3(256), 0, stream,
                     out + (long)B_ * TL * D_,
                     out + (long)B_ * TL * D_ + (long)B_ * TL, TL);
}